// Round 6
// baseline (212.181 us; speedup 1.0000x reference)
//
#include <hip/hip_runtime.h>
#include <cstdint>
#include <cstddef>

typedef _Float16 f16;
typedef f16 f16x8 __attribute__((ext_vector_type(8)));
typedef f16 f16x4 __attribute__((ext_vector_type(4)));
typedef float f32x4 __attribute__((ext_vector_type(4)));

#define SEQ 4096
#define DH 128
#define QKV_LD 384   // 3*DH
#define LOG2E 1.44269504f

__device__ __forceinline__ float fast_exp2(float x) {
#if __has_builtin(__builtin_amdgcn_exp2f)
  return __builtin_amdgcn_exp2f(x);
#else
  return exp2f(x);
#endif
}

// async global->LDS DMA, 16B/lane. LDS dest MUST be wave-uniform base + lane*16.
__device__ __forceinline__ void gl_lds16(const void* g, void* l) {
  __builtin_amdgcn_global_load_lds((const __attribute__((address_space(1))) void*)g,
                                   (__attribute__((address_space(3))) void*)l, 16, 0, 0);
}

// ---------------- W fp32 -> fp16 ----------------
__global__ __launch_bounds__(256) void cvt_w_kernel(const float4* __restrict__ W,
                                                    f16x4* __restrict__ Wh) {
  int i = blockIdx.x * 256 + threadIdx.x;
  float4 v = W[i];
  f16x4 h; h[0] = (f16)v.x; h[1] = (f16)v.y; h[2] = (f16)v.z; h[3] = (f16)v.w;
  Wh[i] = h;
}

// ---------------- QKV GEMM, split-K, LDS for A only ----------------
// BM=64, BN=384, BK=64. Grid (64, SPLITS). B fragments load per-lane DIRECT from
// L2-resident Wh inside the MFMA loop (no LDS tile, no barrier dependence).
// LDS = 9.2 KB A-tile only -> 3 blocks/CU.
template <int SPLITS>
__global__ __launch_bounds__(256, 3) void gemm_qkv(const float* __restrict__ x,
                                                   const f16* __restrict__ Wh,
                                                   f16* __restrict__ part) {
  __shared__ __align__(16) f16 Ax[64][72];   // +8 pad: 144B row stride
  const int m0 = blockIdx.x * 64;
  const int split = blockIdx.y;
  const int kc = SEQ / SPLITS;
  const int k0 = split * kc;
  const int tid = threadIdx.x;
  const int lane = tid & 63;
  const int wave = tid >> 6;
  const int nb = wave * 96;
  const int l15 = lane & 15, quad = lane >> 4;

  f32x4 acc[4][6] = {};

  for (int kt = k0; kt < k0 + kc; kt += 64) {
    // stage A: x[m0..+64][kt..+64] fp32 -> f16 (manual: conversion needed)
#pragma unroll
    for (int r = 0; r < 4; ++r) {
      int c = r * 256 + tid;
      int row = c >> 4, col = (c & 15) * 4;
      float4 v = *(const float4*)&x[(size_t)(m0 + row) * SEQ + kt + col];
      f16x4 h; h[0] = (f16)v.x; h[1] = (f16)v.y; h[2] = (f16)v.z; h[3] = (f16)v.w;
      *(f16x4*)&Ax[row][col] = h;
    }
    __syncthreads();
#pragma unroll
    for (int ks = 0; ks < 2; ++ks) {
      f16x8 a[4], bb[6];
#pragma unroll
      for (int t = 0; t < 4; ++t)
        a[t] = *(const f16x8*)&Ax[t * 16 + l15][ks * 32 + quad * 8];
#pragma unroll
      for (int t = 0; t < 6; ++t)
        bb[t] = *(const f16x8*)&Wh[(size_t)(nb + t * 16 + l15) * SEQ + kt + ks * 32 + quad * 8];
#pragma unroll
      for (int mt = 0; mt < 4; ++mt)
#pragma unroll
        for (int nt = 0; nt < 6; ++nt)
          acc[mt][nt] = __builtin_amdgcn_mfma_f32_16x16x32_f16(a[mt], bb[nt], acc[mt][nt], 0, 0, 0);
    }
    __syncthreads();
  }

  // epilogue: f16 partials
  f16* pw = part + (size_t)split * SEQ * QKV_LD;
#pragma unroll
  for (int mt = 0; mt < 4; ++mt) {
#pragma unroll
    for (int nt = 0; nt < 6; ++nt) {
      int col = nb + nt * 16 + l15;
      int rowbase = m0 + mt * 16 + quad * 4;
#pragma unroll
      for (int rr = 0; rr < 4; ++rr)
        pw[(size_t)(rowbase + rr) * QKV_LD + col] = (f16)acc[mt][nt][rr];
    }
  }
}

// ---------------- reduce split-K partials + bias -> qkv f16 ----------------
template <int SPLITS>
__global__ __launch_bounds__(256) void reduce_qkv(const f16* __restrict__ part,
                                                  const float* __restrict__ bias,
                                                  f16* __restrict__ qkv) {
  int i = (blockIdx.x * 256 + threadIdx.x) * 8;
  float acc[8] = {};
#pragma unroll
  for (int s = 0; s < SPLITS; ++s) {
    f16x8 p = *(const f16x8*)&part[(size_t)s * SEQ * QKV_LD + i];
#pragma unroll
    for (int j = 0; j < 8; ++j) acc[j] += (float)p[j];
  }
  int col = i % QKV_LD;
  f16x8 o;
#pragma unroll
  for (int j = 0; j < 8; ++j) o[j] = (f16)(acc[j] + bias[col + j]);
  *(f16x8*)&qkv[i] = o;
}

// ---------------- transpose V (qkv cols 256..384) -> Vt[128][4096] ----------------
__global__ __launch_bounds__(256) void transpose_v(const f16* __restrict__ qkv,
                                                   f16* __restrict__ Vt) {
  __shared__ __align__(16) f16 T[64][72];
  const int r0 = blockIdx.x * 64;
  const int c0 = blockIdx.y * 64;
  const int tid = threadIdx.x;
#pragma unroll
  for (int rep = 0; rep < 2; ++rep) {
    int idx = rep * 256 + tid;
    int row = idx >> 3, col = (idx & 7) * 8;
    *(f16x8*)&T[row][col] = *(const f16x8*)&qkv[(size_t)(r0 + row) * QKV_LD + 256 + c0 + col];
  }
  __syncthreads();
#pragma unroll
  for (int rep = 0; rep < 2; ++rep) {
    int idx = rep * 256 + tid;
    int cc = idx >> 3, rb = (idx & 7) * 8;
    f16x8 o;
#pragma unroll
    for (int j = 0; j < 8; ++j) o[j] = T[rb + j][cc];
    *(f16x8*)&Vt[(size_t)(c0 + cc) * SEQ + r0 + rb] = o;
  }
}

// ---------------- Flash attention partial over a KV split ----------------
// Wave = 16 q-rows (4 waves = 64/block). S^T = K·Q^T operand-swap scheme.
// Ks/Vs staged by global_load_lds into UNPADDED XOR-swizzled images:
// Ks: 64 keys x 128 d  -> 16 chunks/row, swizzle ch = chg ^ (row&7) (low-3-bit XOR)
// Vs: 128 d  x 64 keys ->  8 chunks/row, swizzle ch = chg ^ (row&7)
#define NSPLIT 16
#define KVRANGE (SEQ / NSPLIT)   // 256

__global__ __launch_bounds__(256, 3) void attn_partial(const f16* __restrict__ qkv,
                                                       const f16* __restrict__ Vt,
                                                       f16* __restrict__ Op,
                                                       float* __restrict__ ml) {
  __shared__ __align__(16) f16 Ks[64 * 128];    // 16 KB, row stride 128 halves
  __shared__ __align__(16) f16 Vs[128 * 64];    // 16 KB, row stride 64 halves
  __shared__ __align__(16) f16 Ps[4][16][72];   // 9.2 KB, padded, per-wave P[m][k]

  const int q0 = blockIdx.x * 64;
  const int split = blockIdx.y;
  const int kv0 = split * KVRANGE;
  const int tid = threadIdx.x;
  const int lane = tid & 63, wave = tid >> 6;
  const int l15 = lane & 15, quad = lane >> 4;
  const int mbase = q0 + wave * 16;

  // Q fragments (pre-scaled by log2 e), used as B-operand of S^T = K·Q^T.
  f16x8 qf[4];
#pragma unroll
  for (int ks = 0; ks < 4; ++ks) {
    f16x8 q = *(const f16x8*)&qkv[(size_t)(mbase + l15) * QKV_LD + ks * 32 + quad * 8];
    qf[ks] = q * (f16)LOG2E;
  }

  f32x4 oacc[8] = {};
  float mrow = -1e30f, lrow = 0.f;

  for (int it = 0; it < KVRANGE / 64; ++it) {
    const int k0 = kv0 + it * 64;
    // Ks: 64 rows x 16 chunks = 1024 chunks, 4/thread. dest c*16B = row*256B + ch*16B
#pragma unroll
    for (int r = 0; r < 4; ++r) {
      int c = r * 256 + tid;
      int row = c >> 4, ch = c & 15;
      gl_lds16(&qkv[(size_t)(k0 + row) * QKV_LD + DH + ((ch ^ (row & 7)) << 3)],
               &Ks[(size_t)c << 3]);
    }
    // Vs: 128 rows x 8 chunks = 1024 chunks, 4/thread
#pragma unroll
    for (int r = 0; r < 4; ++r) {
      int c = r * 256 + tid;
      int row = c >> 3, ch = c & 7;
      gl_lds16(&Vt[(size_t)row * SEQ + k0 + ((ch ^ (row & 7)) << 3)],
               &Vs[(size_t)c << 3]);
    }
    __syncthreads();

    // S^T[k][m]: A=K-frag, B=Q-frag. Lane holds S[m=l15][k=kt*16+quad*4+rr].
    f32x4 st[4] = {};
#pragma unroll
    for (int ks = 0; ks < 4; ++ks) {
      f16x8 kf[4];
#pragma unroll
      for (int kt = 0; kt < 4; ++kt) {
        int row = kt * 16 + l15;
        int ch = (ks * 4 + quad) ^ (row & 7);   // un-swizzle (bit3 of chunk preserved)
        kf[kt] = *(const f16x8*)&Ks[row * 128 + ch * 8];
      }
#pragma unroll
      for (int kt = 0; kt < 4; ++kt)
        st[kt] = __builtin_amdgcn_mfma_f32_16x16x32_f16(kf[kt], qf[ks], st[kt], 0, 0, 0);
    }

    // online softmax: row m = l15; in-lane reduce + 2 shfl over quads
    float v = -1e30f;
#pragma unroll
    for (int kt = 0; kt < 4; ++kt)
#pragma unroll
      for (int rr = 0; rr < 4; ++rr) v = fmaxf(v, st[kt][rr]);
    v = fmaxf(v, __shfl_xor(v, 16));
    v = fmaxf(v, __shfl_xor(v, 32));
    float mnew = fmaxf(mrow, v);
    float al = fast_exp2(mrow - mnew);
    mrow = mnew;
    float ls = 0.f;
#pragma unroll
    for (int kt = 0; kt < 4; ++kt) {
      f16x4 pk;
#pragma unroll
      for (int rr = 0; rr < 4; ++rr) {
        float p = fast_exp2(st[kt][rr] - mnew);
        ls += p;
        pk[rr] = (f16)p;
      }
      *(f16x4*)&Ps[wave][l15][kt * 16 + quad * 4] = pk;   // 4 consecutive k: b64
    }
    ls += __shfl_xor(ls, 16);
    ls += __shfl_xor(ls, 32);
    lrow = lrow * al + ls;

    // alpha (per m=l15) -> O's C-layout rows (m=quad*4+rr)
    float alr[4];
#pragma unroll
    for (int rr = 0; rr < 4; ++rr) alr[rr] = __shfl(al, quad * 4 + rr);
#pragma unroll
    for (int dt = 0; dt < 8; ++dt)
#pragma unroll
      for (int rr = 0; rr < 4; ++rr) oacc[dt][rr] *= alr[rr];

    // PV: A=P-frag (b128, own-wave Ps), B=V^T-frag (swizzled b128)
#pragma unroll
    for (int kk = 0; kk < 2; ++kk) {
      f16x8 pf = *(const f16x8*)&Ps[wave][l15][kk * 32 + quad * 8];
#pragma unroll
      for (int dt = 0; dt < 8; ++dt) {
        int row = dt * 16 + l15;
        int ch = (kk * 4 + quad) ^ (row & 7);
        f16x8 vf = *(const f16x8*)&Vs[row * 64 + ch * 8];
        oacc[dt] = __builtin_amdgcn_mfma_f32_16x16x32_f16(pf, vf, oacc[dt], 0, 0, 0);
      }
    }
    __syncthreads();   // Ks/Vs restaged next iter
  }

  // write partials: rows m = mbase+quad*4+rr, cols d = dt*16+l15
#pragma unroll
  for (int dt = 0; dt < 8; ++dt)
#pragma unroll
    for (int rr = 0; rr < 4; ++rr) {
      int row = mbase + quad * 4 + rr;
      Op[((size_t)split * SEQ + row) * DH + dt * 16 + l15] = (f16)oacc[dt][rr];
    }
  if (quad == 0) {
    int row = mbase + l15;
    ml[((size_t)split * SEQ + row) * 2 + 0] = mrow;
    ml[((size_t)split * SEQ + row) * 2 + 1] = lrow;
  }
}

// ---------------- combine KV splits ----------------
__global__ __launch_bounds__(256) void combine_kernel(const f16* __restrict__ Op,
                                                      const float* __restrict__ ml,
                                                      float* __restrict__ out) {
  int idx = blockIdx.x * 256 + threadIdx.x;
  int row = idx >> 7;
  float ms[NSPLIT], ls[NSPLIT];
  float M = -1e30f;
#pragma unroll
  for (int s = 0; s < NSPLIT; ++s) {
    ms[s] = ml[((size_t)s * SEQ + row) * 2 + 0];
    ls[s] = ml[((size_t)s * SEQ + row) * 2 + 1];
    M = fmaxf(M, ms[s]);
  }
  float L = 0.f, o = 0.f;
#pragma unroll
  for (int s = 0; s < NSPLIT; ++s) {
    float w = fast_exp2(ms[s] - M);   // log2-domain m's
    L += ls[s] * w;
    o += w * (float)Op[(size_t)s * SEQ * DH + idx];
  }
  out[idx] = o / L;
}

extern "C" void kernel_launch(void* const* d_in, const int* in_sizes, int n_in,
                              void* d_out, int out_size, void* d_ws, size_t ws_size,
                              hipStream_t stream) {
  const float* x = (const float*)d_in[0];
  const float* W = (const float*)d_in[1];
  const float* b = (const float*)d_in[2];
  float* out = (float*)d_out;
  char* ws = (char*)d_ws;

  f16*   Wh   = (f16*)(ws);                      // [0, 3M)
  f16*   qkv  = (f16*)(ws + (3u << 20));         // [3M, 6M)
  f16*   Vt   = (f16*)(ws + (6u << 20));         // [6M, 7M)
  float* ml   = (float*)(ws + (7u << 20));       // [7M, 7.5M)
  char*  scr  = ws + (7u << 20) + (1u << 19);    // gemm partials, later Op
  f16*   part = (f16*)scr;                       // SPLITS * 3MB
  f16*   Op   = (f16*)scr;                       // 16 MB (reuses partials region)

  cvt_w_kernel<<<(384 * 4096 / 4) / 256, 256, 0, stream>>>((const float4*)W, (f16x4*)Wh);

  bool big = ws_size >= ((size_t)56u << 20);
  if (big) {
    gemm_qkv<16><<<dim3(SEQ / 64, 16), 256, 0, stream>>>(x, Wh, part);
    reduce_qkv<16><<<SEQ * QKV_LD / 8 / 256, 256, 0, stream>>>(part, b, qkv);
  } else {
    gemm_qkv<8><<<dim3(SEQ / 64, 8), 256, 0, stream>>>(x, Wh, part);
    reduce_qkv<8><<<SEQ * QKV_LD / 8 / 256, 256, 0, stream>>>(part, b, qkv);
  }
  transpose_v<<<dim3(SEQ / 64, DH / 64), 256, 0, stream>>>(qkv, Vt);
  attn_partial<<<dim3(SEQ / 64, NSPLIT), 256, 0, stream>>>(qkv, Vt, Op, ml);
  combine_kernel<<<(SEQ * DH) / 256, 256, 0, stream>>>(Op, ml, out);
}

// Round 7
// 191.732 us; speedup vs baseline: 1.1067x; 1.1067x over previous
//
#include <hip/hip_runtime.h>
#include <cstdint>
#include <cstddef>

typedef _Float16 f16;
typedef f16 f16x8 __attribute__((ext_vector_type(8)));
typedef f16 f16x4 __attribute__((ext_vector_type(4)));
typedef float f32x4 __attribute__((ext_vector_type(4)));

#define SEQ 4096
#define DH 128
#define QKV_LD 384   // 3*DH
#define LOG2E 1.44269504f

__device__ __forceinline__ float fast_exp2(float x) {
#if __has_builtin(__builtin_amdgcn_exp2f)
  return __builtin_amdgcn_exp2f(x);
#else
  return exp2f(x);
#endif
}

// async global->LDS DMA, 16B/lane. LDS dest MUST be wave-uniform base + lane*16.
__device__ __forceinline__ void gl_lds16(const void* g, void* l) {
  __builtin_amdgcn_global_load_lds((const __attribute__((address_space(1))) void*)g,
                                   (__attribute__((address_space(3))) void*)l, 16, 0, 0);
}

// ---------------- W fp32 -> fp16 ----------------
__global__ __launch_bounds__(256) void cvt_w_kernel(const float4* __restrict__ W,
                                                    f16x4* __restrict__ Wh) {
  int i = blockIdx.x * 256 + threadIdx.x;
  float4 v = W[i];
  f16x4 h; h[0] = (f16)v.x; h[1] = (f16)v.y; h[2] = (f16)v.z; h[3] = (f16)v.w;
  Wh[i] = h;
}

// ---------------- QKV GEMM, split-K, BARRIER-FREE (no LDS) ----------------
// BM=64, BN=384, K-step 32. Grid (64, SPLITS). All fragments load per-lane from
// global (A: fp32 x + cvt, redundant across waves -> L1; B: f16 Wh, L2-resident).
// Zero __syncthreads -> compiler pipelines loads across K iterations freely.
template <int SPLITS>
__global__ __launch_bounds__(256, 2) void gemm_qkv(const float* __restrict__ x,
                                                   const f16* __restrict__ Wh,
                                                   f16* __restrict__ part) {
  const int m0 = blockIdx.x * 64;
  const int split = blockIdx.y;
  const int kc = SEQ / SPLITS;
  const int k0 = split * kc;
  const int lane = threadIdx.x & 63;
  const int wave = threadIdx.x >> 6;
  const int nb = wave * 96;
  const int l15 = lane & 15, quad = lane >> 4;

  f32x4 acc[4][6] = {};

  // per-lane row bases: A row = m0 + t*16 + l15 ; B row = nb + t*16 + l15
  const float* pa = &x[(size_t)(m0 + l15) * SEQ + k0 + quad * 8];
  const f16*   pb = &Wh[(size_t)(nb + l15) * SEQ + k0 + quad * 8];

  for (int i = 0; i < kc / 32; ++i) {
    f16x8 a[4];
#pragma unroll
    for (int t = 0; t < 4; ++t) {
      const float* p = pa + (size_t)(t * 16) * SEQ;
      float4 v0 = *(const float4*)p;
      float4 v1 = *(const float4*)(p + 4);
      f16x8 h;
      h[0] = (f16)v0.x; h[1] = (f16)v0.y; h[2] = (f16)v0.z; h[3] = (f16)v0.w;
      h[4] = (f16)v1.x; h[5] = (f16)v1.y; h[6] = (f16)v1.z; h[7] = (f16)v1.w;
      a[t] = h;
    }
    f16x8 b[6];
#pragma unroll
    for (int t = 0; t < 6; ++t)
      b[t] = *(const f16x8*)(pb + (size_t)(t * 16) * SEQ);
#pragma unroll
    for (int mt = 0; mt < 4; ++mt)
#pragma unroll
      for (int nt = 0; nt < 6; ++nt)
        acc[mt][nt] = __builtin_amdgcn_mfma_f32_16x16x32_f16(a[mt], b[nt], acc[mt][nt], 0, 0, 0);
    pa += 32;
    pb += 32;
  }

  // epilogue: f16 partials
  f16* pw = part + (size_t)split * SEQ * QKV_LD;
#pragma unroll
  for (int mt = 0; mt < 4; ++mt) {
#pragma unroll
    for (int nt = 0; nt < 6; ++nt) {
      int col = nb + nt * 16 + l15;
      int rowbase = m0 + mt * 16 + quad * 4;
#pragma unroll
      for (int rr = 0; rr < 4; ++rr)
        pw[(size_t)(rowbase + rr) * QKV_LD + col] = (f16)acc[mt][nt][rr];
    }
  }
}

// ---------------- reduce split-K partials + bias -> qkv f16 ----------------
template <int SPLITS>
__global__ __launch_bounds__(256) void reduce_qkv(const f16* __restrict__ part,
                                                  const float* __restrict__ bias,
                                                  f16* __restrict__ qkv) {
  int i = (blockIdx.x * 256 + threadIdx.x) * 8;
  float acc[8] = {};
#pragma unroll
  for (int s = 0; s < SPLITS; ++s) {
    f16x8 p = *(const f16x8*)&part[(size_t)s * SEQ * QKV_LD + i];
#pragma unroll
    for (int j = 0; j < 8; ++j) acc[j] += (float)p[j];
  }
  int col = i % QKV_LD;
  f16x8 o;
#pragma unroll
  for (int j = 0; j < 8; ++j) o[j] = (f16)(acc[j] + bias[col + j]);
  *(f16x8*)&qkv[i] = o;
}

// ---------------- transpose V (qkv cols 256..384) -> Vt[128][4096] ----------------
__global__ __launch_bounds__(256) void transpose_v(const f16* __restrict__ qkv,
                                                   f16* __restrict__ Vt) {
  __shared__ __align__(16) f16 T[64][72];
  const int r0 = blockIdx.x * 64;
  const int c0 = blockIdx.y * 64;
  const int tid = threadIdx.x;
#pragma unroll
  for (int rep = 0; rep < 2; ++rep) {
    int idx = rep * 256 + tid;
    int row = idx >> 3, col = (idx & 7) * 8;
    *(f16x8*)&T[row][col] = *(const f16x8*)&qkv[(size_t)(r0 + row) * QKV_LD + 256 + c0 + col];
  }
  __syncthreads();
#pragma unroll
  for (int rep = 0; rep < 2; ++rep) {
    int idx = rep * 256 + tid;
    int cc = idx >> 3, rb = (idx & 7) * 8;
    f16x8 o;
#pragma unroll
    for (int j = 0; j < 8; ++j) o[j] = T[rb + j][cc];
    *(f16x8*)&Vt[(size_t)(c0 + cc) * SEQ + r0 + rb] = o;
  }
}

// ---------------- Flash attention partial over a KV split ----------------
// Wave = 16 q-rows (4 waves = 64/block). S^T = K·Q^T operand-swap scheme.
// Ks/Vs staged by global_load_lds into UNPADDED XOR-swizzled images.
#define NSPLIT 16
#define KVRANGE (SEQ / NSPLIT)   // 256

__global__ __launch_bounds__(256, 3) void attn_partial(const f16* __restrict__ qkv,
                                                       const f16* __restrict__ Vt,
                                                       f16* __restrict__ Op,
                                                       float* __restrict__ ml) {
  __shared__ __align__(16) f16 Ks[64 * 128];    // 16 KB, row stride 128 halves
  __shared__ __align__(16) f16 Vs[128 * 64];    // 16 KB, row stride 64 halves
  __shared__ __align__(16) f16 Ps[4][16][72];   // 9.2 KB, padded, per-wave P[m][k]

  const int q0 = blockIdx.x * 64;
  const int split = blockIdx.y;
  const int kv0 = split * KVRANGE;
  const int tid = threadIdx.x;
  const int lane = tid & 63, wave = tid >> 6;
  const int l15 = lane & 15, quad = lane >> 4;
  const int mbase = q0 + wave * 16;

  // Q fragments (pre-scaled by log2 e), used as B-operand of S^T = K·Q^T.
  f16x8 qf[4];
#pragma unroll
  for (int ks = 0; ks < 4; ++ks) {
    f16x8 q = *(const f16x8*)&qkv[(size_t)(mbase + l15) * QKV_LD + ks * 32 + quad * 8];
    qf[ks] = q * (f16)LOG2E;
  }

  f32x4 oacc[8] = {};
  float mrow = -1e30f, lrow = 0.f;

  for (int it = 0; it < KVRANGE / 64; ++it) {
    const int k0 = kv0 + it * 64;
    // Ks: 64 rows x 16 chunks = 1024 chunks, 4/thread
#pragma unroll
    for (int r = 0; r < 4; ++r) {
      int c = r * 256 + tid;
      int row = c >> 4, ch = c & 15;
      gl_lds16(&qkv[(size_t)(k0 + row) * QKV_LD + DH + ((ch ^ (row & 7)) << 3)],
               &Ks[(size_t)c << 3]);
    }
    // Vs: 128 rows x 8 chunks = 1024 chunks, 4/thread
#pragma unroll
    for (int r = 0; r < 4; ++r) {
      int c = r * 256 + tid;
      int row = c >> 3, ch = c & 7;
      gl_lds16(&Vt[(size_t)row * SEQ + k0 + ((ch ^ (row & 7)) << 3)],
               &Vs[(size_t)c << 3]);
    }
    __syncthreads();

    // S^T[k][m]: A=K-frag, B=Q-frag. Lane holds S[m=l15][k=kt*16+quad*4+rr].
    f32x4 st[4] = {};
#pragma unroll
    for (int ks = 0; ks < 4; ++ks) {
      f16x8 kf[4];
#pragma unroll
      for (int kt = 0; kt < 4; ++kt) {
        int row = kt * 16 + l15;
        int ch = (ks * 4 + quad) ^ (row & 7);
        kf[kt] = *(const f16x8*)&Ks[row * 128 + ch * 8];
      }
#pragma unroll
      for (int kt = 0; kt < 4; ++kt)
        st[kt] = __builtin_amdgcn_mfma_f32_16x16x32_f16(kf[kt], qf[ks], st[kt], 0, 0, 0);
    }

    // online softmax: row m = l15; in-lane reduce + 2 shfl over quads
    float v = -1e30f;
#pragma unroll
    for (int kt = 0; kt < 4; ++kt)
#pragma unroll
      for (int rr = 0; rr < 4; ++rr) v = fmaxf(v, st[kt][rr]);
    v = fmaxf(v, __shfl_xor(v, 16));
    v = fmaxf(v, __shfl_xor(v, 32));
    float mnew = fmaxf(mrow, v);
    float al = fast_exp2(mrow - mnew);
    mrow = mnew;
    float ls = 0.f;
#pragma unroll
    for (int kt = 0; kt < 4; ++kt) {
      f16x4 pk;
#pragma unroll
      for (int rr = 0; rr < 4; ++rr) {
        float p = fast_exp2(st[kt][rr] - mnew);
        ls += p;
        pk[rr] = (f16)p;
      }
      *(f16x4*)&Ps[wave][l15][kt * 16 + quad * 4] = pk;   // 4 consecutive k: b64
    }
    ls += __shfl_xor(ls, 16);
    ls += __shfl_xor(ls, 32);
    lrow = lrow * al + ls;

    // alpha (per m=l15) -> O's C-layout rows (m=quad*4+rr)
    float alr[4];
#pragma unroll
    for (int rr = 0; rr < 4; ++rr) alr[rr] = __shfl(al, quad * 4 + rr);
#pragma unroll
    for (int dt = 0; dt < 8; ++dt)
#pragma unroll
      for (int rr = 0; rr < 4; ++rr) oacc[dt][rr] *= alr[rr];

    // PV: A=P-frag (b128, own-wave Ps), B=V^T-frag (swizzled b128)
#pragma unroll
    for (int kk = 0; kk < 2; ++kk) {
      f16x8 pf = *(const f16x8*)&Ps[wave][l15][kk * 32 + quad * 8];
#pragma unroll
      for (int dt = 0; dt < 8; ++dt) {
        int row = dt * 16 + l15;
        int ch = (kk * 4 + quad) ^ (row & 7);
        f16x8 vf = *(const f16x8*)&Vs[row * 64 + ch * 8];
        oacc[dt] = __builtin_amdgcn_mfma_f32_16x16x32_f16(pf, vf, oacc[dt], 0, 0, 0);
      }
    }
    __syncthreads();   // Ks/Vs restaged next iter
  }

  // write partials: rows m = mbase+quad*4+rr, cols d = dt*16+l15
#pragma unroll
  for (int dt = 0; dt < 8; ++dt)
#pragma unroll
    for (int rr = 0; rr < 4; ++rr) {
      int row = mbase + quad * 4 + rr;
      Op[((size_t)split * SEQ + row) * DH + dt * 16 + l15] = (f16)oacc[dt][rr];
    }
  if (quad == 0) {
    int row = mbase + l15;
    ml[((size_t)split * SEQ + row) * 2 + 0] = mrow;
    ml[((size_t)split * SEQ + row) * 2 + 1] = lrow;
  }
}

// ---------------- combine KV splits ----------------
__global__ __launch_bounds__(256) void combine_kernel(const f16* __restrict__ Op,
                                                      const float* __restrict__ ml,
                                                      float* __restrict__ out) {
  int idx = blockIdx.x * 256 + threadIdx.x;
  int row = idx >> 7;
  float ms[NSPLIT], ls[NSPLIT];
  float M = -1e30f;
#pragma unroll
  for (int s = 0; s < NSPLIT; ++s) {
    ms[s] = ml[((size_t)s * SEQ + row) * 2 + 0];
    ls[s] = ml[((size_t)s * SEQ + row) * 2 + 1];
    M = fmaxf(M, ms[s]);
  }
  float L = 0.f, o = 0.f;
#pragma unroll
  for (int s = 0; s < NSPLIT; ++s) {
    float w = fast_exp2(ms[s] - M);   // log2-domain m's
    L += ls[s] * w;
    o += w * (float)Op[(size_t)s * SEQ * DH + idx];
  }
  out[idx] = o / L;
}

extern "C" void kernel_launch(void* const* d_in, const int* in_sizes, int n_in,
                              void* d_out, int out_size, void* d_ws, size_t ws_size,
                              hipStream_t stream) {
  const float* x = (const float*)d_in[0];
  const float* W = (const float*)d_in[1];
  const float* b = (const float*)d_in[2];
  float* out = (float*)d_out;
  char* ws = (char*)d_ws;

  f16*   Wh   = (f16*)(ws);                      // [0, 3M)
  f16*   qkv  = (f16*)(ws + (3u << 20));         // [3M, 6M)
  f16*   Vt   = (f16*)(ws + (6u << 20));         // [6M, 7M)
  float* ml   = (float*)(ws + (7u << 20));       // [7M, 7.5M)
  char*  scr  = ws + (7u << 20) + (1u << 19);    // gemm partials, later Op
  f16*   part = (f16*)scr;                       // SPLITS * 3MB
  f16*   Op   = (f16*)scr;                       // 16 MB (reuses partials region)

  cvt_w_kernel<<<(384 * 4096 / 4) / 256, 256, 0, stream>>>((const float4*)W, (f16x4*)Wh);

  bool big = ws_size >= ((size_t)32u << 20);
  if (big) {
    gemm_qkv<8><<<dim3(SEQ / 64, 8), 256, 0, stream>>>(x, Wh, part);
    reduce_qkv<8><<<SEQ * QKV_LD / 8 / 256, 256, 0, stream>>>(part, b, qkv);
  } else {
    gemm_qkv<4><<<dim3(SEQ / 64, 4), 256, 0, stream>>>(x, Wh, part);
    reduce_qkv<4><<<SEQ * QKV_LD / 8 / 256, 256, 0, stream>>>(part, b, qkv);
  }
  transpose_v<<<dim3(SEQ / 64, DH / 64), 256, 0, stream>>>(qkv, Vt);
  attn_partial<<<dim3(SEQ / 64, NSPLIT), 256, 0, stream>>>(qkv, Vt, Op, ml);
  combine_kernel<<<(SEQ * DH) / 256, 256, 0, stream>>>(Op, ml, out);
}

// Round 8
// 160.656 us; speedup vs baseline: 1.3207x; 1.1934x over previous
//
#include <hip/hip_runtime.h>
#include <cstdint>
#include <cstddef>

typedef _Float16 f16;
typedef f16 f16x8 __attribute__((ext_vector_type(8)));
typedef f16 f16x4 __attribute__((ext_vector_type(4)));
typedef float f32x4 __attribute__((ext_vector_type(4)));

#define SEQ 4096
#define DH 128
#define QKV_LD 384   // 3*DH
#define LOG2E 1.44269504f

__device__ __forceinline__ float fast_exp2(float x) {
#if __has_builtin(__builtin_amdgcn_exp2f)
  return __builtin_amdgcn_exp2f(x);
#else
  return exp2f(x);
#endif
}

// async global->LDS DMA, 16B/lane. LDS dest MUST be wave-uniform base + lane*16.
__device__ __forceinline__ void gl_lds16(const void* g, void* l) {
  __builtin_amdgcn_global_load_lds((const __attribute__((address_space(1))) void*)g,
                                   (__attribute__((address_space(3))) void*)l, 16, 0, 0);
}

// ---------------- generic fp32 -> fp16 (used for W and for x) ----------------
__global__ __launch_bounds__(256) void cvt_kernel(const float4* __restrict__ src,
                                                  f16x4* __restrict__ dst) {
  int i = blockIdx.x * 256 + threadIdx.x;
  float4 v = src[i];
  f16x4 h; h[0] = (f16)v.x; h[1] = (f16)v.y; h[2] = (f16)v.z; h[3] = (f16)v.w;
  dst[i] = h;
}

// ---------------- QKV GEMM: m97-clone. BM=BN=128, BK=64, split-K ----------------
// Both A (xh) and B (Wh) are f16 K-major; both staged via global_load_lds width=16
// into unpadded XOR-swizzled LDS (chunk ^= row&7). 4 waves in 2x2, wave = 64x64.
// Grid (32, 3, SPLITS) = 768 blocks @ SPLITS=8 (~3 blocks/CU; LDS 32 KB).
template <int SPLITS>
__global__ __launch_bounds__(256, 3) void gemm_qkv(const f16* __restrict__ xh,
                                                   const f16* __restrict__ Wh,
                                                   f16* __restrict__ part) {
  __shared__ __align__(16) f16 Ax[128 * 64];   // 16 KB, 8 chunks/row, swizzled
  __shared__ __align__(16) f16 Bx[128 * 64];   // 16 KB
  const int m0 = blockIdx.x * 128;
  const int n0 = blockIdx.y * 128;
  const int split = blockIdx.z;
  const int kc = SEQ / SPLITS;
  const int k0 = split * kc;
  const int tid = threadIdx.x;
  const int lane = tid & 63, wave = tid >> 6;
  const int wr = (wave >> 1) * 64, wc = (wave & 1) * 64;
  const int l15 = lane & 15, quad = lane >> 4;

  f32x4 acc[4][4] = {};

  for (int kt = k0; kt < k0 + kc; kt += 64) {
    // A: 128 rows x 8 chunks = 1024 chunks, 4/thread
#pragma unroll
    for (int r = 0; r < 4; ++r) {
      int c = r * 256 + tid;
      int row = c >> 3, ch = c & 7;
      gl_lds16(&xh[(size_t)(m0 + row) * SEQ + kt + ((ch ^ (row & 7)) << 3)],
               &Ax[(size_t)c << 3]);
    }
    // B: 128 rows x 8 chunks = 1024 chunks, 4/thread
#pragma unroll
    for (int r = 0; r < 4; ++r) {
      int c = r * 256 + tid;
      int row = c >> 3, ch = c & 7;
      gl_lds16(&Wh[(size_t)(n0 + row) * SEQ + kt + ((ch ^ (row & 7)) << 3)],
               &Bx[(size_t)c << 3]);
    }
    __syncthreads();
#pragma unroll
    for (int ks = 0; ks < 2; ++ks) {
      f16x8 a[4], bb[4];
#pragma unroll
      for (int t = 0; t < 4; ++t) {
        int ar = wr + t * 16 + l15;
        int ac = (ks * 4 + quad) ^ (ar & 7);
        a[t] = *(const f16x8*)&Ax[ar * 64 + ac * 8];
        int br = wc + t * 16 + l15;
        int bc = (ks * 4 + quad) ^ (br & 7);
        bb[t] = *(const f16x8*)&Bx[br * 64 + bc * 8];
      }
#pragma unroll
      for (int mt = 0; mt < 4; ++mt)
#pragma unroll
        for (int nt = 0; nt < 4; ++nt)
          acc[mt][nt] = __builtin_amdgcn_mfma_f32_16x16x32_f16(a[mt], bb[nt], acc[mt][nt], 0, 0, 0);
    }
    __syncthreads();
  }

  // epilogue: f16 partials
  f16* pw = part + (size_t)split * SEQ * QKV_LD;
#pragma unroll
  for (int mt = 0; mt < 4; ++mt) {
#pragma unroll
    for (int nt = 0; nt < 4; ++nt) {
      int col = n0 + wc + nt * 16 + l15;
      int rowbase = m0 + wr + mt * 16 + quad * 4;
#pragma unroll
      for (int rr = 0; rr < 4; ++rr)
        pw[(size_t)(rowbase + rr) * QKV_LD + col] = (f16)acc[mt][nt][rr];
    }
  }
}

// ---------------- reduce split-K partials + bias -> qkv f16 ----------------
template <int SPLITS>
__global__ __launch_bounds__(256) void reduce_qkv(const f16* __restrict__ part,
                                                  const float* __restrict__ bias,
                                                  f16* __restrict__ qkv) {
  int i = (blockIdx.x * 256 + threadIdx.x) * 8;
  float acc[8] = {};
#pragma unroll
  for (int s = 0; s < SPLITS; ++s) {
    f16x8 p = *(const f16x8*)&part[(size_t)s * SEQ * QKV_LD + i];
#pragma unroll
    for (int j = 0; j < 8; ++j) acc[j] += (float)p[j];
  }
  int col = i % QKV_LD;
  f16x8 o;
#pragma unroll
  for (int j = 0; j < 8; ++j) o[j] = (f16)(acc[j] + bias[col + j]);
  *(f16x8*)&qkv[i] = o;
}

// ---------------- transpose V (qkv cols 256..384) -> Vt[128][4096] ----------------
__global__ __launch_bounds__(256) void transpose_v(const f16* __restrict__ qkv,
                                                   f16* __restrict__ Vt) {
  __shared__ __align__(16) f16 T[64][72];
  const int r0 = blockIdx.x * 64;
  const int c0 = blockIdx.y * 64;
  const int tid = threadIdx.x;
#pragma unroll
  for (int rep = 0; rep < 2; ++rep) {
    int idx = rep * 256 + tid;
    int row = idx >> 3, col = (idx & 7) * 8;
    *(f16x8*)&T[row][col] = *(const f16x8*)&qkv[(size_t)(r0 + row) * QKV_LD + 256 + c0 + col];
  }
  __syncthreads();
#pragma unroll
  for (int rep = 0; rep < 2; ++rep) {
    int idx = rep * 256 + tid;
    int cc = idx >> 3, rb = (idx & 7) * 8;
    f16x8 o;
#pragma unroll
    for (int j = 0; j < 8; ++j) o[j] = T[rb + j][cc];
    *(f16x8*)&Vt[(size_t)(c0 + cc) * SEQ + r0 + rb] = o;
  }
}

// ---------------- Flash attention partial over a KV split ----------------
// Wave = 16 q-rows (4 waves = 64/block). S^T = K·Q^T operand-swap scheme.
// Ks/Vs staged by global_load_lds into UNPADDED XOR-swizzled images.
#define NSPLIT 16
#define KVRANGE (SEQ / NSPLIT)   // 256

__global__ __launch_bounds__(256, 3) void attn_partial(const f16* __restrict__ qkv,
                                                       const f16* __restrict__ Vt,
                                                       f16* __restrict__ Op,
                                                       float* __restrict__ ml) {
  __shared__ __align__(16) f16 Ks[64 * 128];    // 16 KB, row stride 128 halves
  __shared__ __align__(16) f16 Vs[128 * 64];    // 16 KB, row stride 64 halves
  __shared__ __align__(16) f16 Ps[4][16][72];   // 9.2 KB, padded, per-wave P[m][k]

  const int q0 = blockIdx.x * 64;
  const int split = blockIdx.y;
  const int kv0 = split * KVRANGE;
  const int tid = threadIdx.x;
  const int lane = tid & 63, wave = tid >> 6;
  const int l15 = lane & 15, quad = lane >> 4;
  const int mbase = q0 + wave * 16;

  // Q fragments (pre-scaled by log2 e), used as B-operand of S^T = K·Q^T.
  f16x8 qf[4];
#pragma unroll
  for (int ks = 0; ks < 4; ++ks) {
    f16x8 q = *(const f16x8*)&qkv[(size_t)(mbase + l15) * QKV_LD + ks * 32 + quad * 8];
    qf[ks] = q * (f16)LOG2E;
  }

  f32x4 oacc[8] = {};
  float mrow = -1e30f, lrow = 0.f;

  for (int it = 0; it < KVRANGE / 64; ++it) {
    const int k0 = kv0 + it * 64;
    // Ks: 64 rows x 16 chunks = 1024 chunks, 4/thread
#pragma unroll
    for (int r = 0; r < 4; ++r) {
      int c = r * 256 + tid;
      int row = c >> 4, ch = c & 15;
      gl_lds16(&qkv[(size_t)(k0 + row) * QKV_LD + DH + ((ch ^ (row & 7)) << 3)],
               &Ks[(size_t)c << 3]);
    }
    // Vs: 128 rows x 8 chunks = 1024 chunks, 4/thread
#pragma unroll
    for (int r = 0; r < 4; ++r) {
      int c = r * 256 + tid;
      int row = c >> 3, ch = c & 7;
      gl_lds16(&Vt[(size_t)row * SEQ + k0 + ((ch ^ (row & 7)) << 3)],
               &Vs[(size_t)c << 3]);
    }
    __syncthreads();

    // S^T[k][m]: A=K-frag, B=Q-frag. Lane holds S[m=l15][k=kt*16+quad*4+rr].
    f32x4 st[4] = {};
#pragma unroll
    for (int ks = 0; ks < 4; ++ks) {
      f16x8 kf[4];
#pragma unroll
      for (int kt = 0; kt < 4; ++kt) {
        int row = kt * 16 + l15;
        int ch = (ks * 4 + quad) ^ (row & 7);
        kf[kt] = *(const f16x8*)&Ks[row * 128 + ch * 8];
      }
#pragma unroll
      for (int kt = 0; kt < 4; ++kt)
        st[kt] = __builtin_amdgcn_mfma_f32_16x16x32_f16(kf[kt], qf[ks], st[kt], 0, 0, 0);
    }

    // online softmax: row m = l15; in-lane reduce + 2 shfl over quads
    float v = -1e30f;
#pragma unroll
    for (int kt = 0; kt < 4; ++kt)
#pragma unroll
      for (int rr = 0; rr < 4; ++rr) v = fmaxf(v, st[kt][rr]);
    v = fmaxf(v, __shfl_xor(v, 16));
    v = fmaxf(v, __shfl_xor(v, 32));
    float mnew = fmaxf(mrow, v);
    float al = fast_exp2(mrow - mnew);
    mrow = mnew;
    float ls = 0.f;
#pragma unroll
    for (int kt = 0; kt < 4; ++kt) {
      f16x4 pk;
#pragma unroll
      for (int rr = 0; rr < 4; ++rr) {
        float p = fast_exp2(st[kt][rr] - mnew);
        ls += p;
        pk[rr] = (f16)p;
      }
      *(f16x4*)&Ps[wave][l15][kt * 16 + quad * 4] = pk;   // 4 consecutive k: b64
    }
    ls += __shfl_xor(ls, 16);
    ls += __shfl_xor(ls, 32);
    lrow = lrow * al + ls;

    // alpha (per m=l15) -> O's C-layout rows (m=quad*4+rr)
    float alr[4];
#pragma unroll
    for (int rr = 0; rr < 4; ++rr) alr[rr] = __shfl(al, quad * 4 + rr);
#pragma unroll
    for (int dt = 0; dt < 8; ++dt)
#pragma unroll
      for (int rr = 0; rr < 4; ++rr) oacc[dt][rr] *= alr[rr];

    // PV: A=P-frag (b128, own-wave Ps), B=V^T-frag (swizzled b128)
#pragma unroll
    for (int kk = 0; kk < 2; ++kk) {
      f16x8 pf = *(const f16x8*)&Ps[wave][l15][kk * 32 + quad * 8];
#pragma unroll
      for (int dt = 0; dt < 8; ++dt) {
        int row = dt * 16 + l15;
        int ch = (kk * 4 + quad) ^ (row & 7);
        f16x8 vf = *(const f16x8*)&Vs[row * 64 + ch * 8];
        oacc[dt] = __builtin_amdgcn_mfma_f32_16x16x32_f16(pf, vf, oacc[dt], 0, 0, 0);
      }
    }
    __syncthreads();   // Ks/Vs restaged next iter
  }

  // write partials: rows m = mbase+quad*4+rr, cols d = dt*16+l15
#pragma unroll
  for (int dt = 0; dt < 8; ++dt)
#pragma unroll
    for (int rr = 0; rr < 4; ++rr) {
      int row = mbase + quad * 4 + rr;
      Op[((size_t)split * SEQ + row) * DH + dt * 16 + l15] = (f16)oacc[dt][rr];
    }
  if (quad == 0) {
    int row = mbase + l15;
    ml[((size_t)split * SEQ + row) * 2 + 0] = mrow;
    ml[((size_t)split * SEQ + row) * 2 + 1] = lrow;
  }
}

// ---------------- combine KV splits ----------------
__global__ __launch_bounds__(256) void combine_kernel(const f16* __restrict__ Op,
                                                      const float* __restrict__ ml,
                                                      float* __restrict__ out) {
  int idx = blockIdx.x * 256 + threadIdx.x;
  int row = idx >> 7;
  float ms[NSPLIT], ls[NSPLIT];
  float M = -1e30f;
#pragma unroll
  for (int s = 0; s < NSPLIT; ++s) {
    ms[s] = ml[((size_t)s * SEQ + row) * 2 + 0];
    ls[s] = ml[((size_t)s * SEQ + row) * 2 + 1];
    M = fmaxf(M, ms[s]);
  }
  float L = 0.f, o = 0.f;
#pragma unroll
  for (int s = 0; s < NSPLIT; ++s) {
    float w = fast_exp2(ms[s] - M);   // log2-domain m's
    L += ls[s] * w;
    o += w * (float)Op[(size_t)s * SEQ * DH + idx];
  }
  out[idx] = o / L;
}

extern "C" void kernel_launch(void* const* d_in, const int* in_sizes, int n_in,
                              void* d_out, int out_size, void* d_ws, size_t ws_size,
                              hipStream_t stream) {
  const float* x = (const float*)d_in[0];
  const float* W = (const float*)d_in[1];
  const float* b = (const float*)d_in[2];
  float* out = (float*)d_out;
  char* ws = (char*)d_ws;

  f16*   Wh   = (f16*)(ws);                      // [0, 3M)
  f16*   xh   = (f16*)(ws + (3u << 20));         // [3M, 35M)
  f16*   qkv  = (f16*)(ws + (35u << 20));        // [35M, 38M)
  f16*   Vt   = (f16*)(ws + (38u << 20));        // [38M, 39M)
  float* ml   = (float*)(ws + (39u << 20));      // [39M, 39.5M)
  char*  scr  = ws + (40u << 20);                // gemm partials, later Op
  f16*   part = (f16*)scr;                       // SPLITS * 3MB
  f16*   Op   = (f16*)scr;                       // 16 MB (reuses partials region)

  cvt_kernel<<<(QKV_LD * SEQ / 4) / 256, 256, 0, stream>>>((const float4*)W, (f16x4*)Wh);
  cvt_kernel<<<((size_t)SEQ * SEQ / 4) / 256, 256, 0, stream>>>((const float4*)x, (f16x4*)xh);

  bool big = ws_size >= ((size_t)66u << 20);
  if (big) {
    gemm_qkv<8><<<dim3(SEQ / 128, 3, 8), 256, 0, stream>>>(xh, Wh, part);
    reduce_qkv<8><<<SEQ * QKV_LD / 8 / 256, 256, 0, stream>>>(part, b, qkv);
  } else {
    gemm_qkv<4><<<dim3(SEQ / 128, 3, 4), 256, 0, stream>>>(xh, Wh, part);
    reduce_qkv<4><<<SEQ * QKV_LD / 8 / 256, 256, 0, stream>>>(part, b, qkv);
  }
  transpose_v<<<dim3(SEQ / 64, DH / 64), 256, 0, stream>>>(qkv, Vt);
  attn_partial<<<dim3(SEQ / 64, NSPLIT), 256, 0, stream>>>(qkv, Vt, Op, ml);
  combine_kernel<<<(SEQ * DH) / 256, 256, 0, stream>>>(Op, ml, out);
}

// Round 9
// 158.901 us; speedup vs baseline: 1.3353x; 1.0110x over previous
//
#include <hip/hip_runtime.h>
#include <cstdint>
#include <cstddef>

typedef _Float16 f16;
typedef f16 f16x8 __attribute__((ext_vector_type(8)));
typedef f16 f16x4 __attribute__((ext_vector_type(4)));
typedef float f32x4 __attribute__((ext_vector_type(4)));

#define SEQ 4096
#define DH 128
#define QKV_LD 384   // 3*DH
#define LOG2E 1.44269504f

__device__ __forceinline__ float fast_exp2(float x) {
#if __has_builtin(__builtin_amdgcn_exp2f)
  return __builtin_amdgcn_exp2f(x);
#else
  return exp2f(x);
#endif
}

// async global->LDS DMA, 16B/lane. LDS dest MUST be wave-uniform base + lane*16.
__device__ __forceinline__ void gl_lds16(const void* g, void* l) {
  __builtin_amdgcn_global_load_lds((const __attribute__((address_space(1))) void*)g,
                                   (__attribute__((address_space(3))) void*)l, 16, 0, 0);
}

// ---------------- generic fp32 -> fp16 (used for W and for x) ----------------
__global__ __launch_bounds__(256) void cvt_kernel(const float4* __restrict__ src,
                                                  f16x4* __restrict__ dst) {
  int i = blockIdx.x * 256 + threadIdx.x;
  float4 v = src[i];
  f16x4 h; h[0] = (f16)v.x; h[1] = (f16)v.y; h[2] = (f16)v.z; h[3] = (f16)v.w;
  dst[i] = h;
}

// ---------------- QKV GEMM: m97-clone. BM=BN=128, BK=64, split-K ----------------
// Both A (xh) and B (Wh) f16 K-major; both staged via global_load_lds width=16
// into unpadded XOR-swizzled LDS (chunk ^= row&7). 4 waves in 2x2, wave = 64x64.
// Grid (32, 3, 8) = 768 blocks = 3/CU exactly (LDS 32 KB).
template <int SPLITS>
__global__ __launch_bounds__(256, 3) void gemm_qkv(const f16* __restrict__ xh,
                                                   const f16* __restrict__ Wh,
                                                   f16* __restrict__ part) {
  __shared__ __align__(16) f16 Ax[128 * 64];   // 16 KB, 8 chunks/row, swizzled
  __shared__ __align__(16) f16 Bx[128 * 64];   // 16 KB
  const int m0 = blockIdx.x * 128;
  const int n0 = blockIdx.y * 128;
  const int split = blockIdx.z;
  const int kc = SEQ / SPLITS;
  const int k0 = split * kc;
  const int tid = threadIdx.x;
  const int lane = tid & 63, wave = tid >> 6;
  const int wr = (wave >> 1) * 64, wc = (wave & 1) * 64;
  const int l15 = lane & 15, quad = lane >> 4;

  f32x4 acc[4][4] = {};

  for (int kt = k0; kt < k0 + kc; kt += 64) {
#pragma unroll
    for (int r = 0; r < 4; ++r) {
      int c = r * 256 + tid;
      int row = c >> 3, ch = c & 7;
      gl_lds16(&xh[(size_t)(m0 + row) * SEQ + kt + ((ch ^ (row & 7)) << 3)],
               &Ax[(size_t)c << 3]);
    }
#pragma unroll
    for (int r = 0; r < 4; ++r) {
      int c = r * 256 + tid;
      int row = c >> 3, ch = c & 7;
      gl_lds16(&Wh[(size_t)(n0 + row) * SEQ + kt + ((ch ^ (row & 7)) << 3)],
               &Bx[(size_t)c << 3]);
    }
    __syncthreads();
#pragma unroll
    for (int ks = 0; ks < 2; ++ks) {
      f16x8 a[4], bb[4];
#pragma unroll
      for (int t = 0; t < 4; ++t) {
        int ar = wr + t * 16 + l15;
        int ac = (ks * 4 + quad) ^ (ar & 7);
        a[t] = *(const f16x8*)&Ax[ar * 64 + ac * 8];
        int br = wc + t * 16 + l15;
        int bc = (ks * 4 + quad) ^ (br & 7);
        bb[t] = *(const f16x8*)&Bx[br * 64 + bc * 8];
      }
#pragma unroll
      for (int mt = 0; mt < 4; ++mt)
#pragma unroll
        for (int nt = 0; nt < 4; ++nt)
          acc[mt][nt] = __builtin_amdgcn_mfma_f32_16x16x32_f16(a[mt], bb[nt], acc[mt][nt], 0, 0, 0);
    }
    __syncthreads();
  }

  f16* pw = part + (size_t)split * SEQ * QKV_LD;
#pragma unroll
  for (int mt = 0; mt < 4; ++mt) {
#pragma unroll
    for (int nt = 0; nt < 4; ++nt) {
      int col = n0 + wc + nt * 16 + l15;
      int rowbase = m0 + wr + mt * 16 + quad * 4;
#pragma unroll
      for (int rr = 0; rr < 4; ++rr)
        pw[(size_t)(rowbase + rr) * QKV_LD + col] = (f16)acc[mt][nt][rr];
    }
  }
}

// ---------------- reduce split-K partials + bias -> qkv f16 ----------------
template <int SPLITS>
__global__ __launch_bounds__(256) void reduce_qkv(const f16* __restrict__ part,
                                                  const float* __restrict__ bias,
                                                  f16* __restrict__ qkv) {
  int i = (blockIdx.x * 256 + threadIdx.x) * 8;
  float acc[8] = {};
#pragma unroll
  for (int s = 0; s < SPLITS; ++s) {
    f16x8 p = *(const f16x8*)&part[(size_t)s * SEQ * QKV_LD + i];
#pragma unroll
    for (int j = 0; j < 8; ++j) acc[j] += (float)p[j];
  }
  int col = i % QKV_LD;
  f16x8 o;
#pragma unroll
  for (int j = 0; j < 8; ++j) o[j] = (f16)(acc[j] + bias[col + j]);
  *(f16x8*)&qkv[i] = o;
}

// ---------------- transpose V (qkv cols 256..384) -> Vt[128][4096] ----------------
__global__ __launch_bounds__(256) void transpose_v(const f16* __restrict__ qkv,
                                                   f16* __restrict__ Vt) {
  __shared__ __align__(16) f16 T[64][72];
  const int r0 = blockIdx.x * 64;
  const int c0 = blockIdx.y * 64;
  const int tid = threadIdx.x;
#pragma unroll
  for (int rep = 0; rep < 2; ++rep) {
    int idx = rep * 256 + tid;
    int row = idx >> 3, col = (idx & 7) * 8;
    *(f16x8*)&T[row][col] = *(const f16x8*)&qkv[(size_t)(r0 + row) * QKV_LD + 256 + c0 + col];
  }
  __syncthreads();
#pragma unroll
  for (int rep = 0; rep < 2; ++rep) {
    int idx = rep * 256 + tid;
    int cc = idx >> 3, rb = (idx & 7) * 8;
    f16x8 o;
#pragma unroll
    for (int j = 0; j < 8; ++j) o[j] = T[rb + j][cc];
    *(f16x8*)&Vt[(size_t)(c0 + cc) * SEQ + r0 + rb] = o;
  }
}

// ---------------- Flash attention partial over a KV split ----------------
// Wave = 32 q-rows (BM=128). S^T = K·Q^T operand-swap scheme; per kt-iter the
// kf/vf LDS reads are amortized over 2 m-tiles (64 MFMA per ~470 LDS cyc).
// Ks/Vs staged by global_load_lds into UNPADDED XOR-swizzled images.
#define NSPLIT 16
#define KVRANGE (SEQ / NSPLIT)   // 256

__global__ __launch_bounds__(256, 2) void attn_partial(const f16* __restrict__ qkv,
                                                       const f16* __restrict__ Vt,
                                                       f16* __restrict__ Op,
                                                       float* __restrict__ ml) {
  __shared__ __align__(16) f16 Ks[64 * 128];    // 16 KB, row stride 128 halves
  __shared__ __align__(16) f16 Vs[128 * 64];    // 16 KB, row stride 64 halves
  __shared__ __align__(16) f16 Ps[4][32][72];   // 18.4 KB, per-wave P[m][k]

  const int q0 = blockIdx.x * 128;
  const int split = blockIdx.y;
  const int kv0 = split * KVRANGE;
  const int tid = threadIdx.x;
  const int lane = tid & 63, wave = tid >> 6;
  const int l15 = lane & 15, quad = lane >> 4;
  const int mbase = q0 + wave * 32;

  // Q fragments (pre-scaled by log2 e), B-operand of S^T = K·Q^T.
  f16x8 qf[2][4];
#pragma unroll
  for (int mt = 0; mt < 2; ++mt)
#pragma unroll
    for (int ks = 0; ks < 4; ++ks) {
      f16x8 q = *(const f16x8*)&qkv[(size_t)(mbase + mt * 16 + l15) * QKV_LD + ks * 32 + quad * 8];
      qf[mt][ks] = q * (f16)LOG2E;
    }

  f32x4 oacc[2][8] = {};
  float mrow[2] = {-1e30f, -1e30f};
  float lrow[2] = {0.f, 0.f};

  for (int it = 0; it < KVRANGE / 64; ++it) {
    const int k0 = kv0 + it * 64;
    // Ks: 64 rows x 16 chunks = 1024 chunks, 4/thread
#pragma unroll
    for (int r = 0; r < 4; ++r) {
      int c = r * 256 + tid;
      int row = c >> 4, ch = c & 15;
      gl_lds16(&qkv[(size_t)(k0 + row) * QKV_LD + DH + ((ch ^ (row & 7)) << 3)],
               &Ks[(size_t)c << 3]);
    }
    // Vs: 128 rows x 8 chunks = 1024 chunks, 4/thread
#pragma unroll
    for (int r = 0; r < 4; ++r) {
      int c = r * 256 + tid;
      int row = c >> 3, ch = c & 7;
      gl_lds16(&Vt[(size_t)row * SEQ + k0 + ((ch ^ (row & 7)) << 3)],
               &Vs[(size_t)c << 3]);
    }
    __syncthreads();

    // S^T[k][m]: A=K-frag, B=Q-frag. Lane holds S[m=mt*16+l15][k=kt*16+quad*4+rr].
    f32x4 st[4][2] = {};
#pragma unroll
    for (int ks = 0; ks < 4; ++ks) {
      f16x8 kf[4];
#pragma unroll
      for (int kt = 0; kt < 4; ++kt) {
        int row = kt * 16 + l15;
        int ch = (ks * 4 + quad) ^ (row & 7);
        kf[kt] = *(const f16x8*)&Ks[row * 128 + ch * 8];
      }
#pragma unroll
      for (int kt = 0; kt < 4; ++kt)
#pragma unroll
        for (int mt = 0; mt < 2; ++mt)
          st[kt][mt] = __builtin_amdgcn_mfma_f32_16x16x32_f16(kf[kt], qf[mt][ks], st[kt][mt], 0, 0, 0);
    }

    // online softmax per m-tile: row m = l15; in-lane reduce + 2 shfl over quads
    float al[2];
#pragma unroll
    for (int mt = 0; mt < 2; ++mt) {
      float v = -1e30f;
#pragma unroll
      for (int kt = 0; kt < 4; ++kt)
#pragma unroll
        for (int rr = 0; rr < 4; ++rr) v = fmaxf(v, st[kt][mt][rr]);
      v = fmaxf(v, __shfl_xor(v, 16));
      v = fmaxf(v, __shfl_xor(v, 32));
      float mnew = fmaxf(mrow[mt], v);
      al[mt] = fast_exp2(mrow[mt] - mnew);
      mrow[mt] = mnew;
      float ls = 0.f;
#pragma unroll
      for (int kt = 0; kt < 4; ++kt) {
        f16x4 pk;
#pragma unroll
        for (int rr = 0; rr < 4; ++rr) {
          float p = fast_exp2(st[kt][mt][rr] - mnew);
          ls += p;
          pk[rr] = (f16)p;
        }
        *(f16x4*)&Ps[wave][mt * 16 + l15][kt * 16 + quad * 4] = pk;  // b64
      }
      ls += __shfl_xor(ls, 16);
      ls += __shfl_xor(ls, 32);
      lrow[mt] = lrow[mt] * al[mt] + ls;
    }

    // alpha (per m=l15) -> O's C-layout rows (m=quad*4+rr)
    float alr[2][4];
#pragma unroll
    for (int mt = 0; mt < 2; ++mt)
#pragma unroll
      for (int rr = 0; rr < 4; ++rr) alr[mt][rr] = __shfl(al[mt], quad * 4 + rr);
#pragma unroll
    for (int mt = 0; mt < 2; ++mt)
#pragma unroll
      for (int dt = 0; dt < 8; ++dt)
#pragma unroll
        for (int rr = 0; rr < 4; ++rr) oacc[mt][dt][rr] *= alr[mt][rr];

    // PV: A=P-frag (b128, own-wave Ps), B=V^T-frag (swizzled b128); vf shared by both mt
#pragma unroll
    for (int kk = 0; kk < 2; ++kk) {
      f16x8 pf[2];
#pragma unroll
      for (int mt = 0; mt < 2; ++mt)
        pf[mt] = *(const f16x8*)&Ps[wave][mt * 16 + l15][kk * 32 + quad * 8];
#pragma unroll
      for (int dt = 0; dt < 8; ++dt) {
        int row = dt * 16 + l15;
        int ch = (kk * 4 + quad) ^ (row & 7);
        f16x8 vf = *(const f16x8*)&Vs[row * 64 + ch * 8];
#pragma unroll
        for (int mt = 0; mt < 2; ++mt)
          oacc[mt][dt] = __builtin_amdgcn_mfma_f32_16x16x32_f16(pf[mt], vf, oacc[mt][dt], 0, 0, 0);
      }
    }
    __syncthreads();   // Ks/Vs restaged next iter
  }

  // write partials: rows m = mbase+mt*16+quad*4+rr, cols d = dt*16+l15
#pragma unroll
  for (int mt = 0; mt < 2; ++mt)
#pragma unroll
    for (int dt = 0; dt < 8; ++dt)
#pragma unroll
      for (int rr = 0; rr < 4; ++rr) {
        int row = mbase + mt * 16 + quad * 4 + rr;
        Op[((size_t)split * SEQ + row) * DH + dt * 16 + l15] = (f16)oacc[mt][dt][rr];
      }
  if (quad == 0) {
#pragma unroll
    for (int mt = 0; mt < 2; ++mt) {
      int row = mbase + mt * 16 + l15;
      ml[((size_t)split * SEQ + row) * 2 + 0] = mrow[mt];
      ml[((size_t)split * SEQ + row) * 2 + 1] = lrow[mt];
    }
  }
}

// ---------------- combine KV splits ----------------
__global__ __launch_bounds__(256) void combine_kernel(const f16* __restrict__ Op,
                                                      const float* __restrict__ ml,
                                                      float* __restrict__ out) {
  int idx = blockIdx.x * 256 + threadIdx.x;
  int row = idx >> 7;
  float ms[NSPLIT], ls[NSPLIT];
  float M = -1e30f;
#pragma unroll
  for (int s = 0; s < NSPLIT; ++s) {
    ms[s] = ml[((size_t)s * SEQ + row) * 2 + 0];
    ls[s] = ml[((size_t)s * SEQ + row) * 2 + 1];
    M = fmaxf(M, ms[s]);
  }
  float L = 0.f, o = 0.f;
#pragma unroll
  for (int s = 0; s < NSPLIT; ++s) {
    float w = fast_exp2(ms[s] - M);   // log2-domain m's
    L += ls[s] * w;
    o += w * (float)Op[(size_t)s * SEQ * DH + idx];
  }
  out[idx] = o / L;
}

extern "C" void kernel_launch(void* const* d_in, const int* in_sizes, int n_in,
                              void* d_out, int out_size, void* d_ws, size_t ws_size,
                              hipStream_t stream) {
  const float* x = (const float*)d_in[0];
  const float* W = (const float*)d_in[1];
  const float* b = (const float*)d_in[2];
  float* out = (float*)d_out;
  char* ws = (char*)d_ws;

  f16*   Wh   = (f16*)(ws);                      // [0, 3M)
  f16*   xh   = (f16*)(ws + (3u << 20));         // [3M, 35M)
  f16*   qkv  = (f16*)(ws + (35u << 20));        // [35M, 38M)
  f16*   Vt   = (f16*)(ws + (38u << 20));        // [38M, 39M)
  float* ml   = (float*)(ws + (39u << 20));      // [39M, 39.5M)
  char*  scr  = ws + (40u << 20);                // gemm partials, later Op
  f16*   part = (f16*)scr;                       // SPLITS * 3MB
  f16*   Op   = (f16*)scr;                       // 16 MB (reuses partials region)

  cvt_kernel<<<(QKV_LD * SEQ / 4) / 256, 256, 0, stream>>>((const float4*)W, (f16x4*)Wh);
  cvt_kernel<<<((size_t)SEQ * SEQ / 4) / 256, 256, 0, stream>>>((const float4*)x, (f16x4*)xh);

  bool big = ws_size >= ((size_t)66u << 20);
  if (big) {
    gemm_qkv<8><<<dim3(SEQ / 128, 3, 8), 256, 0, stream>>>(xh, Wh, part);
    reduce_qkv<8><<<SEQ * QKV_LD / 8 / 256, 256, 0, stream>>>(part, b, qkv);
  } else {
    gemm_qkv<4><<<dim3(SEQ / 128, 3, 4), 256, 0, stream>>>(xh, Wh, part);
    reduce_qkv<4><<<SEQ * QKV_LD / 8 / 256, 256, 0, stream>>>(part, b, qkv);
  }
  transpose_v<<<dim3(SEQ / 64, DH / 64), 256, 0, stream>>>(qkv, Vt);
  attn_partial<<<dim3(SEQ / 128, NSPLIT), 256, 0, stream>>>(qkv, Vt, Op, ml);
  combine_kernel<<<(SEQ * DH) / 256, 256, 0, stream>>>(Op, ml, out);
}